// Round 20
// baseline (91.491 us; speedup 1.0000x reference)
//
#include <hip/hip_runtime.h>

// KANConv2d, round 20: two independent barrier domains per CU — race-free version.
// R19's failure was a cross-wave DMA race: pre-reading a buffer DMA'd in the SAME
// substep (vmcnt only drains the local wave's chunks). Fix: drop the cross-substep
// register pre-read entirely; every buffer read is sealed by a prior barrier
// (own-wave vmcnt BEFORE the barrier -> cross-wave visible after it, R6 invariant).
// The post-barrier refill stall is instead hidden by the ANTI-PHASE second block.
//
// Structure: grid 512 (16b x 32 h-pairs), 256 thr = 4 waves (2 ohalf x 2 hrow),
//   block = 128o x 64w x 2h, LDS 66KB -> 2 blocks/CU with separate hw barriers.
//   A: global_load_lds DMA, double-buffered At[2], depth-1 prefetch, counted vmcnt.
//   B: features in-kernel, single-buffered Bt; FEATW barrier pair per cb.
//
// out[b,o,h,w] = sum_{c,tap,j} Wc[o,c,tap,j] * f_j(xp[b,c,h+dh,w+dw])
// f = {silu(v), B_0..B_6(v)} cardinal cubic B-splines (t = 2v+5), 8 bf16/granule.

#define BB 16
#define CC 64
#define HH 64
#define WW 64
#define OO 128

typedef __bf16 bf16x8 __attribute__((ext_vector_type(8)));
typedef float f32x16 __attribute__((ext_vector_type(16)));

__device__ __forceinline__ bf16x8 as_bf16x8(uint4 v) { return __builtin_bit_cast(bf16x8, v); }
__device__ __forceinline__ unsigned bfb(float f) {
    return (unsigned)__builtin_bit_cast(unsigned short, (__bf16)f);
}

// 8-feature granule {silu(v), B_0(v)..B_6(v)} packed as 8 bf16 via 128-bit shift scatter.
__device__ __forceinline__ uint4 feat_granule(float v) {
    const float silu = __fdividef(v, 1.f + __expf(-v));
    const float t  = fmaf(2.f, v, 5.f);
    const float fi = floorf(t);
    const float u  = t - fi;
    const float um = 1.f - u;
    const float u2 = u * u, u3 = u2 * u;
    const float k0 = um * um * um * (1.f / 6.f);
    const float k1 = fmaf(0.5f, u3, (2.f / 3.f) - u2);
    const float k2 = fmaf(-0.5f, u3, fmaf(0.5f, u2, fmaf(0.5f, u, 1.f / 6.f)));
    const float k3 = u3 * (1.f / 6.f);
    const bool valid = (t >= 0.f) && (t < 10.f);
    unsigned long long K =
        (unsigned long long)bfb(k0)         |
        ((unsigned long long)bfb(k1) << 16) |
        ((unsigned long long)bfb(k2) << 32) |
        ((unsigned long long)bfb(k3) << 48);
    if (!valid) K = 0ull;
    const int ic = min(max((int)fi, -2), 9);
    const int sh = 16 * ic - 32;            // [-64, 112]
    unsigned __int128 P = (sh >= 0) ? ((unsigned __int128)K << sh)
                                    : ((unsigned __int128)K >> (-sh));
    uint4 pk = __builtin_bit_cast(uint4, P);
    pk.x = (pk.x & 0xFFFF0000u) | bfb(silu);
    return pk;
}

// ---------------- weight prep: Wb[cb][tap][c_l][o][j] bf16, j contiguous ----------------
__global__ __launch_bounds__(256) void kan_wprep(
    const float* __restrict__ beta, const float* __restrict__ spl,
    const float* __restrict__ cf, uint4* __restrict__ wb)
{
    int t = blockIdx.x * 256 + threadIdx.x;      // 73728 = (o, c, tap)
    int tap = t % 9;
    int c   = (t / 9) & 63;
    int o   = t / 576;
    int base = (o * CC + c) * 9 + tap;
    float bv = beta[base];
    float sv = spl[base];
    float f[8];
    f[0] = bv;
    #pragma unroll
    for (int s = 0; s < 7; ++s)
        f[1 + s] = sv * cf[((s * OO + o) * CC + c) * 9 + tap];
    uint4 pk;
    pk.x = bfb(f[0]) | (bfb(f[1]) << 16);
    pk.y = bfb(f[2]) | (bfb(f[3]) << 16);
    pk.z = bfb(f[4]) | (bfb(f[5]) << 16);
    pk.w = bfb(f[6]) | (bfb(f[7]) << 16);
    int cb = c >> 2, cl = c & 3;
    wb[((cb * 9 + tap) * 4 + cl) * OO + o] = pk;
}

// ---------------- main implicit GEMM ----------------
__global__ __launch_bounds__(256, 2) void kan_mfma17(
    const float* __restrict__ x, const uint4* __restrict__ wb,
    float* __restrict__ out)
{
    // B/features: [cl][row 0..3][col 0..65] single buffer, 1056 granules (16.9KB)
    __shared__ uint4 Bt[1056];
    // A/weights substep tile: double buffered (49.2KB); total 66KB -> 2 blocks/CU
    __shared__ uint4 At[2][1536];

    const int tid  = threadIdx.x;
    const int blk  = blockIdx.x;
    const int hp   = blk & 31;         // h-pair index
    const int b    = blk >> 5;
    const int h0   = hp << 1;          // output rows h0, h0+1; input rows h0-1..h0+2

    const int ww    = tid >> 6;        // wave 0..3
    const int lane  = tid & 63;
    const int lo    = lane & 31;
    const int hi    = lane >> 5;
    const int ohalf = ww & 1;
    const int hrow  = ww >> 1;         // 0..1

    f32x16 acc[2][2] = {};             // [oi][wi]
    float xv[5];

    // ---- x loads for channel-block cbi: 1056 granule-pixels (4cl x 4rows x 66) ----
    #define XLOAD(cbi) do {                                                   \
        _Pragma("unroll")                                                     \
        for (int k = 0; k < 5; ++k) {                                         \
            const int g = tid + k * 256;                                      \
            float v = 0.f;                                                    \
            if (g < 1056) {                                                   \
                const int cl_ = g / 264;                                      \
                const int r_  = (g % 264) / 66;                               \
                const int co_ = g % 66;                                       \
                const int hx  = h0 - 1 + r_;                                  \
                const int wx  = co_ - 1;                                      \
                if ((unsigned)hx < 64u && (unsigned)wx < 64u)                 \
                    v = x[((b * CC + (cbi) * 4 + cl_) * HH + hx) * WW + wx];  \
            }                                                                 \
            xv[k] = v;                                                        \
        }                                                                     \
    } while (0)

    // ---- feature compute + LDS write into Bt ----
    #define FEATW() do {                                                      \
        _Pragma("unroll")                                                     \
        for (int k = 0; k < 5; ++k) {                                         \
            const int g = tid + k * 256;                                      \
            if (g < 1056) Bt[g] = feat_granule(xv[k]);                        \
        }                                                                     \
    } while (0)

    // ---- DMA one A substep slice (cb1, dh1) into At[bufi]: 24 x 1KB, 6/wave ----
    #define ADMA(bufi, cb1, dh1) do {                                         \
        const uint4* asrc = wb + ((cb1) * 4608 + (dh1) * 1536)                \
                            + ww * 384 + lane;                                \
        _Pragma("unroll")                                                     \
        for (int i = 0; i < 6; ++i)                                           \
            __builtin_amdgcn_global_load_lds(                                 \
                (const __attribute__((address_space(1))) void*)(asrc + i*64), \
                (__attribute__((address_space(3))) void*)                     \
                    &At[bufi][ww * 384 + i * 64],                             \
                16, 0, 0);                                                    \
    } while (0)

    #define READ_A(dst, Ab, tl) do {                                          \
        _Pragma("unroll")                                                     \
        for (int kh = 0; kh < 2; ++kh) {                                      \
            const int arow = ((tl) * 4 + kh * 2 + hi) * 128 + ohalf * 64 + lo;\
            dst[kh][0] = (Ab)[arow];                                          \
            dst[kh][1] = (Ab)[arow + 32];                                     \
        }                                                                     \
    } while (0)

    #define READ_B(dst, dhv, tl) do {                                         \
        _Pragma("unroll")                                                     \
        for (int kh = 0; kh < 2; ++kh) {                                      \
            const int brow = ((kh * 2 + hi) * 4 + hrow + (dhv)) * 66          \
                             + (tl) + lo;                                     \
            dst[kh][0] = Bt[brow];                                            \
            dst[kh][1] = Bt[brow + 32];                                       \
        }                                                                     \
    } while (0)

    #define MFMA8(A_, B_) do {                                                \
        _Pragma("unroll")                                                     \
        for (int oi = 0; oi < 2; ++oi)                                        \
            _Pragma("unroll")                                                 \
            for (int wi = 0; wi < 2; ++wi)                                    \
                _Pragma("unroll")                                             \
                for (int kh = 0; kh < 2; ++kh)                                \
                    acc[oi][wi] = __builtin_amdgcn_mfma_f32_32x32x16_bf16(    \
                        as_bf16x8(A_[kh][oi]), as_bf16x8(B_[kh][wi]),         \
                        acc[oi][wi], 0, 0, 0);                                \
    } while (0)

    // prologue: Bt <- features(cb0); At[0] <- (0,0); full drain; barrier seals both
    XLOAD(0);
    ADMA(0, 0, 0);
    FEATW();
    asm volatile("s_waitcnt vmcnt(0) lgkmcnt(0)" ::: "memory");
    __builtin_amdgcn_s_barrier();
    __builtin_amdgcn_sched_barrier(0);

    #pragma unroll 1
    for (int cb = 0; cb < 16; ++cb) {
        #pragma unroll
        for (int dh = 0; dh < 3; ++dh) {
            const int s = cb * 3 + dh;          // substep; reads At[s&1] (sealed)
            const uint4* Ab = At[(cb + dh) & 1];

            // top: depth-1 A-DMA for s+1 into the other buffer (its readers done
            // before the previous barrier); x loads for next cb at dh0.
            if (s < 47) {
                const int cb1 = (dh == 2) ? cb + 1 : cb;
                const int dh1 = (dh == 2) ? 0 : dh + 1;
                ADMA((cb + dh + 1) & 1, cb1, dh1);
            }
            if (dh == 0 && cb < 15) {
                __builtin_amdgcn_sched_barrier(0);   // keep ADMA oldest in vm queue
                XLOAD(cb + 1);
            }

            // ---- 3 tap columns, all reads from sealed buffers ----
            #pragma unroll
            for (int tl = 0; tl < 3; ++tl) {
                uint4 a[2][2], bfr[2][2];
                READ_A(a, Ab, tl);
                READ_B(bfr, dh, tl);
                MFMA8(a, bfr);
            }

            // ---- end-of-substep: own-DMA drain BEFORE barrier -> cross-wave seal ----
            if (dh == 2) {
                if (cb < 15) {
                    __builtin_amdgcn_s_barrier();    // Bt reads done in all waves
                    FEATW();                         // republish Bt for cb+1
                    // seal FEATW (lgkm) and the cb+1 dh0 A-DMA (vmcnt own chunks)
                    asm volatile("s_waitcnt vmcnt(0) lgkmcnt(0)" ::: "memory");
                    __builtin_amdgcn_s_barrier();
                    __builtin_amdgcn_sched_barrier(0);
                }
            } else {
                if (dh == 0 && cb < 15) {
                    // newer than this substep's ADMA: the 5 XLOAD dwords
                    asm volatile("s_waitcnt vmcnt(5)" ::: "memory");
                } else {
                    asm volatile("s_waitcnt vmcnt(0)" ::: "memory");
                }
                __builtin_amdgcn_s_barrier();
                __builtin_amdgcn_sched_barrier(0);
            }
        }
    }

    // ---- store: w-coalesced dword stores ----
    const int h = h0 + hrow;
    #pragma unroll
    for (int oi = 0; oi < 2; ++oi)
        #pragma unroll
        for (int wi = 0; wi < 2; ++wi) {
            const int wc = wi * 32 + lo;
            #pragma unroll
            for (int r = 0; r < 16; ++r) {
                const int o = ohalf * 64 + oi * 32 + (r & 3) + ((r >> 2) << 3) + (hi << 2);
                out[((b * OO + o) * HH + h) * WW + wc] = acc[oi][wi][r];
            }
        }
}

extern "C" void kernel_launch(void* const* d_in, const int* in_sizes, int n_in,
                              void* d_out, int out_size, void* d_ws, size_t ws_size,
                              hipStream_t stream) {
    const float* x    = (const float*)d_in[0];
    const float* beta = (const float*)d_in[1];
    const float* spl  = (const float*)d_in[2];
    const float* cf   = (const float*)d_in[3];
    float* out = (float*)d_out;
    uint4* wb  = (uint4*)d_ws;          // 73728 granules = 1.18 MB

    kan_wprep<<<288, 256, 0, stream>>>(beta, spl, cf, wb);
    kan_mfma17<<<BB * 32, 256, 0, stream>>>(x, wb, out);
}